// Round 1
// baseline (574.849 us; speedup 1.0000x reference)
//
#include <hip/hip_runtime.h>
#include <cstdint>

// Problem constants (LocalizedFiltering: B=4, S=4096, D=2048, DH=1024)
#define BB 4
#define SS 4096           // power of 2: t = r & 4095, b = r >> 12
#define DD 2048
#define DH 1024
#define MM (BB * SS)      // 16384 rows
#define EPSV 1e-6f

typedef unsigned short u16;
typedef __bf16 bf16x8 __attribute__((ext_vector_type(8)));
typedef float f32x4 __attribute__((ext_vector_type(4)));

// ---------- helpers ----------

__device__ __forceinline__ u16 f2bf(float f) {           // RNE f32 -> bf16 bits
    uint32_t u = __float_as_uint(f);
    u += 0x7fffu + ((u >> 16) & 1u);
    return (u16)(u >> 16);
}

// async global->LDS, 16B per lane. LDS dest is wave-uniform base + lane*16.
__device__ __forceinline__ void async16(const void* g, void* l) {
    __builtin_amdgcn_global_load_lds(
        (const __attribute__((address_space(1))) uint32_t*)g,
        (__attribute__((address_space(3))) uint32_t*)l,
        16, 0, 0);
}

#define FENCE asm volatile("" ::: "memory")

// ---------- elementwise converts / packs ----------

__global__ void cvt_f32_bf16(const float* __restrict__ in, u16* __restrict__ out, long n4) {
    long i = (long)blockIdx.x * blockDim.x + threadIdx.x;
    if (i >= n4) return;
    float4 v = *(const float4*)(in + i * 4);
    ushort4 o;
    o.x = f2bf(v.x); o.y = f2bf(v.y); o.z = f2bf(v.z); o.w = f2bf(v.w);
    *(ushort4*)(out + i * 4) = o;
}

// w [Nr, Dd, 2] f32 (tap-interleaved) -> out [Nr, 2*Dd] bf16 with tap0 cols [0,Dd), tap1 [Dd,2Dd)
__global__ void pack_w(const float* __restrict__ in, u16* __restrict__ out, int dshift) {
    int idx = blockIdx.x * 256 + threadIdx.x;   // pair index: e*Dd + d
    int Dd = 1 << dshift;
    int e = idx >> dshift;
    int d = idx & (Dd - 1);
    float2 v = *(const float2*)(in + (long)idx * 2);
    long rowbase = (long)e * (Dd * 2);
    out[rowbase + d] = f2bf(v.x);          // tap 0 (prev timestep)
    out[rowbase + Dd + d] = f2bf(v.y);     // tap 1 (current timestep)
}

// ---------- shifted 2-tap GEMM: 256x256 tile, BK=64, 8-wave 8-phase deep pipeline ----------
//
// LDS (128 KiB): sm elem index = d*32768 + mat*16384 + ks*8192 + row*32 + kelem
//   d = double-buffer (tile t -> buf t&1), mat: 0=A 1=B, ks = K-half (32 elems),
//   row = 0..255 (A: output rows; B: output cols), kelem = 0..31.
// Swizzle: LDS 16B-slot s of row r holds global 16B-chunk  s ^ ((r>>1)&3).
//   Staged via pre-swizzled GLOBAL per-lane address (global_load_lds dest is
//   linear base+lane*16); read side applies the same XOR -> frag ds_read_b128
//   lands 2 lanes per 4-bank group per 16-lane quarter (conflict-free).
// Staging round (mat,ks,h): 8 KB = 128 rows x 32 elems; lane l -> row l>>2,
//   slot l&3; global chunk (l&3)^((l>>3)&3). 2 rounds (h=0,1) = 1 sub-tile.
// Phases per tile (2 barriers each):  p0:(ks0,n0/1)  p1:(ks0,n2/3)  p2:(ks1,n0/1)  p3:(ks1,n2/3)
// Staging schedule: t.p0 -> (t+1) A-K1 ; t.p1 -> (t+1) B-K1 ; t.p2 -> (t+2) A-K0 ; t.p3 -> (t+2) B-K0
//   (regions written are always >=2 barriers past their last reader).
// Waits: s_waitcnt vmcnt(8) at p1-end and p3-end (8 per-thread loads are always
//   issued after the sub-tiles the next reads need). Prologue stages t0 fully +
//   t1's K0 (12 loads), vmcnt(8). Tail peeled with vmcnt(4)/vmcnt(0).
//
// C[r,n] = sum_{k<KD} Bt[n,k]*Aprev[r,k] + sum_{k<KD} Bt[n,KD+k]*Acur[r,k]
// Aprev row r = (r%S==0) ? cache[r/S] : A[r-1]
// MODE 1: out bf16 [M,NN] + bias; rows with t==S-1 also stored f32 to lf2out
// MODE 2: out f32  [M,NN] + bias + residual xres
template <int KD, int MODE>
__launch_bounds__(512, 2)
__global__ void gemm2tap(const u16* __restrict__ A,       // [M, KD] bf16
                         const u16* __restrict__ cache,   // [B, KD] bf16
                         const u16* __restrict__ Bt,      // [NN, 2*KD] bf16
                         const float* __restrict__ bias,  // [NN]
                         u16* __restrict__ obf,           // MODE 1
                         float* __restrict__ lf2out,      // MODE 1
                         const float* __restrict__ xres,  // MODE 2
                         float* __restrict__ yout)        // MODE 2
{
    constexpr int KTOT = 2 * KD;
    constexpr int NT = KTOT / 64;      // K-tiles of 64
    constexpr int HALF_T = NT / 2;     // tap boundary in tiles
    constexpr int NN = (MODE == 1) ? DH : DD;
    static_assert(NT >= 4 && (NT & 1) == 0, "tile schedule needs even NT >= 4");

    const int tid = threadIdx.x;
    const int lane = tid & 63;
    const int wave = tid >> 6;         // 8 waves: wm = wave>>2 (2), wn = wave&3 (4)
    const int bm = blockIdx.x;
    const int bn = blockIdx.y;

    __shared__ __align__(16) u16 sm[65536];   // 128 KiB

    // ---- staging addressing ----
    const int srow = wave * 16 + (lane >> 2);          // row within 128-row half
    const int skc  = (lane & 3) ^ ((lane >> 3) & 3);   // pre-swizzled global chunk
    const int sRowA = wave * 512;                      // wave-uniform LDS elem offset

    const u16 *aPrev0, *aPrev1, *aCur0, *aCur1, *bPtr0, *bPtr1;
    {
        long r0 = (long)bm * 256 + srow;
        long r1 = r0 + 128;
        aCur0 = A + r0 * KD + skc * 8;
        aCur1 = A + r1 * KD + skc * 8;
        aPrev0 = ((((int)r0) & (SS - 1)) == 0) ? (cache + (r0 >> 12) * KD + skc * 8)
                                               : (A + (r0 - 1) * KD + skc * 8);
        aPrev1 = ((((int)r1) & (SS - 1)) == 0) ? (cache + (r1 >> 12) * KD + skc * 8)
                                               : (A + (r1 - 1) * KD + skc * 8);
        long n0l = (long)bn * 256 + srow;
        bPtr0 = Bt + n0l * KTOT + skc * 8;
        bPtr1 = Bt + (n0l + 128) * KTOT + skc * 8;
    }

#define STAGE_A(DBUF_, TT_, KS_) do {                                          \
        const int _ko = (TT_) * 64 + (KS_) * 32;                               \
        const u16 *_g0, *_g1;                                                  \
        if ((TT_) < HALF_T) { _g0 = aPrev0 + _ko; _g1 = aPrev1 + _ko; }        \
        else { _g0 = aCur0 + (_ko - KD); _g1 = aCur1 + (_ko - KD); }           \
        async16(_g0, sm + (DBUF_) * 32768 + (KS_) * 8192 + sRowA);             \
        async16(_g1, sm + (DBUF_) * 32768 + (KS_) * 8192 + 4096 + sRowA);      \
    } while (0)

#define STAGE_B(DBUF_, TT_, KS_) do {                                          \
        const int _ko = (TT_) * 64 + (KS_) * 32;                               \
        async16(bPtr0 + _ko, sm + (DBUF_) * 32768 + 16384 + (KS_) * 8192 + sRowA);        \
        async16(bPtr1 + _ko, sm + (DBUF_) * 32768 + 16384 + (KS_) * 8192 + 4096 + sRowA); \
    } while (0)

    // ---- fragment read addressing ----
    const int frow = lane & 15;
    const int fquad = lane >> 4;
    const int wm128 = (wave >> 2) * 128;
    const int wn64  = (wave & 3) * 64;
    const int fq8s = (fquad ^ ((frow >> 1) & 3)) * 8;  // swizzled 16B chunk (elems)
    const int afb = (wm128 + frow) * 32 + fq8s;
    const int bfb = (wn64 + frow) * 32 + fq8s;

    f32x4 acc[8][4];
#pragma unroll
    for (int i = 0; i < 8; ++i)
#pragma unroll
        for (int j = 0; j < 4; ++j)
            acc[i][j] = (f32x4){0.f, 0.f, 0.f, 0.f};

#define MFMA_(D_, A_, B_) D_ = __builtin_amdgcn_mfma_f32_16x16x32_bf16(A_, B_, D_, 0, 0, 0)

#define TILE(T_, DB_, S01_, S23_, VM1S_, VM3S_)                                \
  {                                                                            \
    const u16* aro = sm + (DB_) * 32768;                                       \
    const u16* bro = aro + 16384;                                              \
    bf16x8 af[8], bq0, bq1;                                                    \
    /* -- phase 0: ks=0, n-frags 0,1 -- */                                     \
    _Pragma("unroll")                                                          \
    for (int mf = 0; mf < 8; ++mf)                                             \
        af[mf] = *(const bf16x8*)(aro + afb + mf * 512);                       \
    bq0 = *(const bf16x8*)(bro + bfb);                                         \
    bq1 = *(const bf16x8*)(bro + bfb + 512);                                   \
    if (S01_) STAGE_A((DB_) ^ 1, (T_) + 1, 1);                                 \
    FENCE; __builtin_amdgcn_s_barrier();                                       \
    asm volatile("s_waitcnt lgkmcnt(0)" ::: "memory");                         \
    __builtin_amdgcn_sched_barrier(0);                                         \
    __builtin_amdgcn_s_setprio(1);                                             \
    _Pragma("unroll")                                                          \
    for (int mf = 0; mf < 8; ++mf) {                                           \
        MFMA_(acc[mf][0], af[mf], bq0);                                        \
        MFMA_(acc[mf][1], af[mf], bq1);                                        \
    }                                                                          \
    __builtin_amdgcn_s_setprio(0);                                             \
    FENCE; __builtin_amdgcn_s_barrier(); FENCE;                                \
    /* -- phase 1: ks=0, n-frags 2,3 -- */                                     \
    bq0 = *(const bf16x8*)(bro + bfb + 1024);                                  \
    bq1 = *(const bf16x8*)(bro + bfb + 1536);                                  \
    if (S01_) STAGE_B((DB_) ^ 1, (T_) + 1, 1);                                 \
    FENCE; __builtin_amdgcn_s_barrier();                                       \
    asm volatile("s_waitcnt lgkmcnt(0)" ::: "memory");                         \
    __builtin_amdgcn_sched_barrier(0);                                         \
    __builtin_amdgcn_s_setprio(1);                                             \
    _Pragma("unroll")                                                          \
    for (int mf = 0; mf < 8; ++mf) {                                           \
        MFMA_(acc[mf][2], af[mf], bq0);                                        \
        MFMA_(acc[mf][3], af[mf], bq1);                                        \
    }                                                                          \
    __builtin_amdgcn_s_setprio(0);                                             \
    asm volatile(VM1S_ ::: "memory");                                          \
    __builtin_amdgcn_s_barrier(); FENCE;                                       \
    /* -- phase 2: ks=1, n-frags 0,1 -- */                                     \
    _Pragma("unroll")                                                          \
    for (int mf = 0; mf < 8; ++mf)                                             \
        af[mf] = *(const bf16x8*)(aro + 8192 + afb + mf * 512);                \
    bq0 = *(const bf16x8*)(bro + 8192 + bfb);                                  \
    bq1 = *(const bf16x8*)(bro + 8192 + bfb + 512);                            \
    if (S23_) STAGE_A((DB_), (T_) + 2, 0);                                     \
    FENCE; __builtin_amdgcn_s_barrier();                                       \
    asm volatile("s_waitcnt lgkmcnt(0)" ::: "memory");                         \
    __builtin_amdgcn_sched_barrier(0);                                         \
    __builtin_amdgcn_s_setprio(1);                                             \
    _Pragma("unroll")                                                          \
    for (int mf = 0; mf < 8; ++mf) {                                           \
        MFMA_(acc[mf][0], af[mf], bq0);                                        \
        MFMA_(acc[mf][1], af[mf], bq1);                                        \
    }                                                                          \
    __builtin_amdgcn_s_setprio(0);                                             \
    FENCE; __builtin_amdgcn_s_barrier(); FENCE;                                \
    /* -- phase 3: ks=1, n-frags 2,3 -- */                                     \
    bq0 = *(const bf16x8*)(bro + 8192 + bfb + 1024);                           \
    bq1 = *(const bf16x8*)(bro + 8192 + bfb + 1536);                           \
    if (S23_) STAGE_B((DB_), (T_) + 2, 0);                                     \
    FENCE; __builtin_amdgcn_s_barrier();                                       \
    asm volatile("s_waitcnt lgkmcnt(0)" ::: "memory");                         \
    __builtin_amdgcn_sched_barrier(0);                                         \
    __builtin_amdgcn_s_setprio(1);                                             \
    _Pragma("unroll")                                                          \
    for (int mf = 0; mf < 8; ++mf) {                                           \
        MFMA_(acc[mf][2], af[mf], bq0);                                        \
        MFMA_(acc[mf][3], af[mf], bq1);                                        \
    }                                                                          \
    __builtin_amdgcn_s_setprio(0);                                             \
    asm volatile(VM3S_ ::: "memory");                                          \
    __builtin_amdgcn_s_barrier(); FENCE;                                       \
  }

    // ---- prologue: stage tile0 fully + tile1 K0 (12 loads), in count order ----
    STAGE_A(0, 0, 0);
    STAGE_B(0, 0, 0);
    FENCE;                       // pin issue order: t0-K0 loads are the oldest 4
    STAGE_A(0, 0, 1);
    STAGE_B(0, 0, 1);
    STAGE_A(1, 1, 0);
    STAGE_B(1, 1, 0);
    asm volatile("s_waitcnt vmcnt(8)" ::: "memory");   // t0 K0 staged
    __builtin_amdgcn_s_barrier(); FENCE;

    // ---- main loop: tiles 0 .. NT-3 (full staging, uniform vmcnt(8)) ----
    for (int t = 0; t < NT - 2; t += 2) {
        TILE(t,     0, 1, 1, "s_waitcnt vmcnt(8)", "s_waitcnt vmcnt(8)");
        TILE(t + 1, 1, 1, 1, "s_waitcnt vmcnt(8)", "s_waitcnt vmcnt(8)");
    }
    // ---- tail: tile NT-2 stages only (NT-1)'s K1; tile NT-1 stages nothing ----
    TILE(NT - 2, 0, 1, 0, "s_waitcnt vmcnt(8)", "s_waitcnt vmcnt(4)");
    TILE(NT - 1, 1, 0, 0, "s_waitcnt vmcnt(0)", "s_waitcnt vmcnt(0)");

#undef TILE
#undef STAGE_A
#undef STAGE_B

    // ---- epilogue; C/D layout: col = lane&15, row = (lane>>4)*4 + v ----
    const long m0 = (long)bm * 256 + wm128;
    const int n0 = bn * 256 + wn64;
#pragma unroll
    for (int mf = 0; mf < 8; ++mf) {
#pragma unroll
        for (int nf = 0; nf < 4; ++nf) {
            const int n = n0 + nf * 16 + frow;
            const float bv = bias[n];
#pragma unroll
            for (int v = 0; v < 4; ++v) {
                const long m = m0 + mf * 16 + fquad * 4 + v;
                float val = acc[mf][nf][v] + bv;
                if (MODE == 1) {
                    obf[m * NN + n] = f2bf(val);
                    if ((((int)m) & (SS - 1)) == (SS - 1))
                        lf2out[(m >> 12) * NN + n] = val;   // new lf2 cache (f32)
                } else {
                    val += xres[m * NN + n];                // residual in f32
                    yout[m * NN + n] = val;
                }
            }
        }
    }
}

// ---------- RMSNorm (in-place on d_out rows) ----------

__global__ void rmsnorm_inplace(float* __restrict__ y, const float* __restrict__ lnw) {
    const long r = blockIdx.x;
    float* row = y + r * DD;
    const int tid = threadIdx.x;

    float4 v0 = *(float4*)(row + tid * 4);
    float4 v1 = *(float4*)(row + 1024 + tid * 4);
    float s = v0.x * v0.x + v0.y * v0.y + v0.z * v0.z + v0.w * v0.w
            + v1.x * v1.x + v1.y * v1.y + v1.z * v1.z + v1.w * v1.w;
#pragma unroll
    for (int off = 32; off; off >>= 1) s += __shfl_xor(s, off, 64);

    __shared__ float red[4];
    if ((tid & 63) == 0) red[tid >> 6] = s;
    __syncthreads();
    float tot = red[0] + red[1] + red[2] + red[3];
    float inv = rsqrtf(tot * (1.0f / DD) + EPSV);

    float4 w0 = *(const float4*)(lnw + tid * 4);
    float4 w1 = *(const float4*)(lnw + 1024 + tid * 4);
    v0.x *= inv * w0.x; v0.y *= inv * w0.y; v0.z *= inv * w0.z; v0.w *= inv * w0.w;
    v1.x *= inv * w1.x; v1.y *= inv * w1.y; v1.z *= inv * w1.z; v1.w *= inv * w1.w;
    *(float4*)(row + tid * 4) = v0;
    *(float4*)(row + 1024 + tid * 4) = v1;
}

// lf1 = x[:, S-1, :]  (f32 copy, B*D = 8192 elems)
__global__ void lf1_copy(const float* __restrict__ x, float* __restrict__ out) {
    int idx = blockIdx.x * 256 + threadIdx.x;   // 0..8191
    int b = idx >> 11;
    int d = idx & (DD - 1);
    out[idx] = x[((long)b * SS + (SS - 1)) * DD + d];
}

// ---------- launch ----------

extern "C" void kernel_launch(void* const* d_in, const int* in_sizes, int n_in,
                              void* d_out, int out_size, void* d_ws, size_t ws_size,
                              hipStream_t stream) {
    const float* x    = (const float*)d_in[0];   // [M, D]
    const float* lf1c = (const float*)d_in[1];   // [B, D]
    const float* lf2c = (const float*)d_in[2];   // [B, DH]
    const float* w1   = (const float*)d_in[3];   // [DH, D, 2]
    const float* b1   = (const float*)d_in[4];   // [DH]
    const float* w2   = (const float*)d_in[5];   // [D, DH, 2]
    const float* b2   = (const float*)d_in[6];   // [D]
    const float* lnw  = (const float*)d_in[7];   // [D]

    float* out    = (float*)d_out;                        // lf_output [M, D]
    float* lf1out = out + (long)MM * DD;                  // [B, D]
    float* lf2out = lf1out + (long)BB * DD;               // [B, DH]

    char* ws = (char*)d_ws;
    u16* Xbf  = (u16*)ws; ws += (long)MM * DD * 2;        // 67.1 MB
    u16* o1bf = (u16*)ws; ws += (long)MM * DH * 2;        // 33.6 MB
    u16* W1b  = (u16*)ws; ws += (long)DH * (2 * DD) * 2;  // 8.4 MB
    u16* W2b  = (u16*)ws; ws += (long)DD * (2 * DH) * 2;  // 8.4 MB
    u16* c1   = (u16*)ws; ws += (long)BB * DD * 2;
    u16* c2   = (u16*)ws; ws += (long)BB * DH * 2;

    // 1) converts & weight packing
    cvt_f32_bf16<<<32768, 256, 0, stream>>>(x, Xbf, (long)MM * DD / 4);
    cvt_f32_bf16<<<8, 256, 0, stream>>>(lf1c, c1, (long)BB * DD / 4);
    cvt_f32_bf16<<<4, 256, 0, stream>>>(lf2c, c2, (long)BB * DH / 4);
    pack_w<<<(DH * DD) / 256, 256, 0, stream>>>(w1, W1b, 11);   // Dd = D = 2048
    pack_w<<<(DD * DH) / 256, 256, 0, stream>>>(w2, W2b, 10);   // Dd = DH = 1024

    // 2) conv1 GEMM: [M, 2D] x [2D, DH] -> o1 bf16 (+ lf2 rows f32)
    gemm2tap<DD, 1><<<dim3(MM / 256, DH / 256), 512, 0, stream>>>(
        Xbf, c1, W1b, b1, o1bf, lf2out, nullptr, nullptr);

    // 3) conv2 GEMM: [M, 2DH] x [2DH, D] -> y = o2 + x (f32, into d_out)
    gemm2tap<DH, 2><<<dim3(MM / 256, DD / 256), 512, 0, stream>>>(
        o1bf, c2, W2b, b2, nullptr, nullptr, x, out);

    // 4) RMSNorm in place + lf1 cache copy
    rmsnorm_inplace<<<MM, 256, 0, stream>>>(out, lnw);
    lf1_copy<<<BB * DD / 256, 256, 0, stream>>>(x, lf1out);
}

// Round 2
// 571.002 us; speedup vs baseline: 1.0067x; 1.0067x over previous
//
#include <hip/hip_runtime.h>
#include <cstdint>

// Problem constants (LocalizedFiltering: B=4, S=4096, D=2048, DH=1024)
#define BB 4
#define SS 4096           // power of 2: t = r & 4095, b = r >> 12
#define DD 2048
#define DH 1024
#define MM (BB * SS)      // 16384 rows
#define EPSV 1e-6f

typedef unsigned short u16;
typedef __bf16 bf16x8 __attribute__((ext_vector_type(8)));
typedef float f32x4 __attribute__((ext_vector_type(4)));

// ---------- helpers ----------

__device__ __forceinline__ u16 f2bf(float f) {           // RNE f32 -> bf16 bits
    uint32_t u = __float_as_uint(f);
    u += 0x7fffu + ((u >> 16) & 1u);
    return (u16)(u >> 16);
}

// async global->LDS, 16B per lane. LDS dest is wave-uniform base + lane*16.
__device__ __forceinline__ void async16(const void* g, void* l) {
    __builtin_amdgcn_global_load_lds(
        (const __attribute__((address_space(1))) uint32_t*)g,
        (__attribute__((address_space(3))) uint32_t*)l,
        16, 0, 0);
}

#define FENCE asm volatile("" ::: "memory")

// ---------- elementwise converts / packs ----------

__global__ void cvt_f32_bf16(const float* __restrict__ in, u16* __restrict__ out, long n4) {
    long i = (long)blockIdx.x * blockDim.x + threadIdx.x;
    if (i >= n4) return;
    float4 v = *(const float4*)(in + i * 4);
    ushort4 o;
    o.x = f2bf(v.x); o.y = f2bf(v.y); o.z = f2bf(v.z); o.w = f2bf(v.w);
    *(ushort4*)(out + i * 4) = o;
}

// w [Nr, Dd, 2] f32 (tap-interleaved) -> out [Nr, 2*Dd] bf16 with tap0 cols [0,Dd), tap1 [Dd,2Dd)
__global__ void pack_w(const float* __restrict__ in, u16* __restrict__ out, int dshift) {
    int idx = blockIdx.x * 256 + threadIdx.x;   // pair index: e*Dd + d
    int Dd = 1 << dshift;
    int e = idx >> dshift;
    int d = idx & (Dd - 1);
    float2 v = *(const float2*)(in + (long)idx * 2);
    long rowbase = (long)e * (Dd * 2);
    out[rowbase + d] = f2bf(v.x);          // tap 0 (prev timestep)
    out[rowbase + Dd + d] = f2bf(v.y);     // tap 1 (current timestep)
}

// ---------- shifted 2-tap GEMM: 256x256 tile, BK=64, 8-wave, 2 fat phases/K-tile ----------
//
// LDS (128 KiB): sm elem index = d*32768 + mat*16384 + ks*8192 + row*32 + kelem
//   d = double-buffer (tile t -> buf t&1), mat: 0=A 1=B, ks = K-half (32 elems),
//   row = 0..255 (A: output rows; B: output cols), kelem = 0..31.
// Swizzle: LDS 16B-slot s of row r holds global 16B-chunk  s ^ ((r>>1)&3).
//   Staged via pre-swizzled GLOBAL per-lane address (global_load_lds dest is
//   linear base+lane*16); read side applies the same XOR -> frag ds_read_b128
//   conflict-free (verified: SQ_LDS_BANK_CONFLICT == 0 in round 1).
// Phase structure (round-2 change: 2 fat phases per K-tile, was 4 thin ones):
//   phase = { 12 ds_read_b128 (8 A-frags + 4 B-frags, one K-half)
//             stage 4 global_load_lds (A+B of one future sub-tile)
//             barrier ; setprio(1) ; 32 MFMA ; setprio(0) ; vmcnt(N) ; barrier }
//   Rationale: round-1 counters showed ~850 cyc fixed overhead per phase vs
//   621 cyc of MFMA -> halve the number of phases, double MFMA per phase.
//   No explicit lgkmcnt(0)/sched_barrier(0): ds_reads are compiler-visible, so
//   hipcc emits fine-grained lgkmcnt(N) interleaved with the MFMAs.
// Staging schedule: t.p0 -> (t+1) K1 [buf^1] ; t.p1 -> (t+2) K0 [buf].
//   WAR safe: region staged in a phase was last READ in the previous phase;
//   those reads' data fed MFMAs before the intervening trailing barrier.
// vmcnt: 4 loads/thread/phase. Steady state: at each phase end the sub-tile the
//   NEXT phase reads has exactly 8 younger loads -> uniform vmcnt(8).
//   Prologue stages t0K0,t0K1,t1K0 (12 loads), waits vmcnt(8) (t0K0 done).
//   Tail: (NT-2).p1 end vmcnt(4); (NT-1) vmcnt(0).
//
// C[r,n] = sum_{k<KD} Bt[n,k]*Aprev[r,k] + sum_{k<KD} Bt[n,KD+k]*Acur[r,k]
// Aprev row r = (r%S==0) ? cache[r/S] : A[r-1]
// MODE 1: out bf16 [M,NN] + bias; rows with t==S-1 also stored f32 to lf2out
// MODE 2: out f32  [M,NN] + bias + residual xres
template <int KD, int MODE>
__launch_bounds__(512, 2)
__global__ void gemm2tap(const u16* __restrict__ A,       // [M, KD] bf16
                         const u16* __restrict__ cache,   // [B, KD] bf16
                         const u16* __restrict__ Bt,      // [NN, 2*KD] bf16
                         const float* __restrict__ bias,  // [NN]
                         u16* __restrict__ obf,           // MODE 1
                         float* __restrict__ lf2out,      // MODE 1
                         const float* __restrict__ xres,  // MODE 2
                         float* __restrict__ yout)        // MODE 2
{
    constexpr int KTOT = 2 * KD;
    constexpr int NT = KTOT / 64;      // K-tiles of 64
    constexpr int HALF_T = NT / 2;     // tap boundary in tiles
    constexpr int NN = (MODE == 1) ? DH : DD;
    static_assert(NT >= 4 && (NT & 1) == 0, "tile schedule needs even NT >= 4");

    const int tid = threadIdx.x;
    const int lane = tid & 63;
    const int wave = tid >> 6;         // 8 waves: wm = wave>>2 (2), wn = wave&3 (4)
    const int bm = blockIdx.x;
    const int bn = blockIdx.y;

    __shared__ __align__(16) u16 sm[65536];   // 128 KiB

    // ---- staging addressing ----
    const int srow = wave * 16 + (lane >> 2);          // row within 128-row half
    const int skc  = (lane & 3) ^ ((lane >> 3) & 3);   // pre-swizzled global chunk
    const int sRowA = wave * 512;                      // wave-uniform LDS elem offset

    const u16 *aPrev0, *aPrev1, *aCur0, *aCur1, *bPtr0, *bPtr1;
    {
        long r0 = (long)bm * 256 + srow;
        long r1 = r0 + 128;
        aCur0 = A + r0 * KD + skc * 8;
        aCur1 = A + r1 * KD + skc * 8;
        aPrev0 = ((((int)r0) & (SS - 1)) == 0) ? (cache + (r0 >> 12) * KD + skc * 8)
                                               : (A + (r0 - 1) * KD + skc * 8);
        aPrev1 = ((((int)r1) & (SS - 1)) == 0) ? (cache + (r1 >> 12) * KD + skc * 8)
                                               : (A + (r1 - 1) * KD + skc * 8);
        long n0l = (long)bn * 256 + srow;
        bPtr0 = Bt + n0l * KTOT + skc * 8;
        bPtr1 = Bt + (n0l + 128) * KTOT + skc * 8;
    }

#define STAGE_A(DBUF_, TT_, KS_) do {                                          \
        const int _ko = (TT_) * 64 + (KS_) * 32;                               \
        const u16 *_g0, *_g1;                                                  \
        if ((TT_) < HALF_T) { _g0 = aPrev0 + _ko; _g1 = aPrev1 + _ko; }        \
        else { _g0 = aCur0 + (_ko - KD); _g1 = aCur1 + (_ko - KD); }           \
        async16(_g0, sm + (DBUF_) * 32768 + (KS_) * 8192 + sRowA);             \
        async16(_g1, sm + (DBUF_) * 32768 + (KS_) * 8192 + 4096 + sRowA);      \
    } while (0)

#define STAGE_B(DBUF_, TT_, KS_) do {                                          \
        const int _ko = (TT_) * 64 + (KS_) * 32;                               \
        async16(bPtr0 + _ko, sm + (DBUF_) * 32768 + 16384 + (KS_) * 8192 + sRowA);        \
        async16(bPtr1 + _ko, sm + (DBUF_) * 32768 + 16384 + (KS_) * 8192 + 4096 + sRowA); \
    } while (0)

    // ---- fragment read addressing ----
    const int frow = lane & 15;
    const int fquad = lane >> 4;
    const int wm128 = (wave >> 2) * 128;
    const int wn64  = (wave & 3) * 64;
    const int fq8s = (fquad ^ ((frow >> 1) & 3)) * 8;  // swizzled 16B chunk (elems)
    const int afb = (wm128 + frow) * 32 + fq8s;
    const int bfb = (wn64 + frow) * 32 + fq8s;

    f32x4 acc[8][4];
#pragma unroll
    for (int i = 0; i < 8; ++i)
#pragma unroll
        for (int j = 0; j < 4; ++j)
            acc[i][j] = (f32x4){0.f, 0.f, 0.f, 0.f};

#define MFMA_(D_, A_, B_) D_ = __builtin_amdgcn_mfma_f32_16x16x32_bf16(A_, B_, D_, 0, 0, 0)

#define TILE2(T_, DB_, SP0_, SP1_, VM0S_, VM1S_)                               \
  {                                                                            \
    const u16* aro = sm + (DB_) * 32768;                                       \
    const u16* bro = aro + 16384;                                              \
    bf16x8 af[8], bq[4];                                                       \
    /* -- phase 0: K-half 0, all 4 n-frags -- */                               \
    _Pragma("unroll")                                                          \
    for (int mf = 0; mf < 8; ++mf)                                             \
        af[mf] = *(const bf16x8*)(aro + afb + mf * 512);                       \
    _Pragma("unroll")                                                          \
    for (int nf = 0; nf < 4; ++nf)                                             \
        bq[nf] = *(const bf16x8*)(bro + bfb + nf * 512);                       \
    if (SP0_) { STAGE_A((DB_) ^ 1, (T_) + 1, 1); STAGE_B((DB_) ^ 1, (T_) + 1, 1); } \
    FENCE; __builtin_amdgcn_s_barrier(); FENCE;                                \
    __builtin_amdgcn_s_setprio(1);                                             \
    _Pragma("unroll")                                                          \
    for (int mf = 0; mf < 8; ++mf)                                             \
        _Pragma("unroll")                                                      \
        for (int nf = 0; nf < 4; ++nf)                                         \
            MFMA_(acc[mf][nf], af[mf], bq[nf]);                                \
    __builtin_amdgcn_s_setprio(0);                                             \
    asm volatile(VM0S_ ::: "memory");                                          \
    __builtin_amdgcn_s_barrier(); FENCE;                                       \
    /* -- phase 1: K-half 1, all 4 n-frags -- */                               \
    _Pragma("unroll")                                                          \
    for (int mf = 0; mf < 8; ++mf)                                             \
        af[mf] = *(const bf16x8*)(aro + 8192 + afb + mf * 512);                \
    _Pragma("unroll")                                                          \
    for (int nf = 0; nf < 4; ++nf)                                             \
        bq[nf] = *(const bf16x8*)(bro + 8192 + bfb + nf * 512);                \
    if (SP1_) { STAGE_A((DB_), (T_) + 2, 0); STAGE_B((DB_), (T_) + 2, 0); }    \
    FENCE; __builtin_amdgcn_s_barrier(); FENCE;                                \
    __builtin_amdgcn_s_setprio(1);                                             \
    _Pragma("unroll")                                                          \
    for (int mf = 0; mf < 8; ++mf)                                             \
        _Pragma("unroll")                                                      \
        for (int nf = 0; nf < 4; ++nf)                                         \
            MFMA_(acc[mf][nf], af[mf], bq[nf]);                                \
    __builtin_amdgcn_s_setprio(0);                                             \
    asm volatile(VM1S_ ::: "memory");                                          \
    __builtin_amdgcn_s_barrier(); FENCE;                                       \
  }

    // ---- prologue: stage t0-K0, t0-K1, t1-K0 (12 loads), in count order ----
    STAGE_A(0, 0, 0);
    STAGE_B(0, 0, 0);
    FENCE;                       // pin issue order: t0-K0 loads are the oldest 4
    STAGE_A(0, 0, 1);
    STAGE_B(0, 0, 1);
    STAGE_A(1, 1, 0);
    STAGE_B(1, 1, 0);
    asm volatile("s_waitcnt vmcnt(8)" ::: "memory");   // t0 K0 staged
    __builtin_amdgcn_s_barrier(); FENCE;

    // ---- main loop: tiles 0 .. NT-3 (full staging, uniform vmcnt(8)) ----
    for (int t = 0; t < NT - 2; t += 2) {
        TILE2(t,     0, 1, 1, "s_waitcnt vmcnt(8)", "s_waitcnt vmcnt(8)");
        TILE2(t + 1, 1, 1, 1, "s_waitcnt vmcnt(8)", "s_waitcnt vmcnt(8)");
    }
    // ---- tail: tile NT-2 stages only (NT-1)'s K1; tile NT-1 stages nothing ----
    TILE2(NT - 2, 0, 1, 0, "s_waitcnt vmcnt(8)", "s_waitcnt vmcnt(4)");
    TILE2(NT - 1, 1, 0, 0, "s_waitcnt vmcnt(0)", "s_waitcnt vmcnt(0)");

#undef TILE2
#undef STAGE_A
#undef STAGE_B

    // ---- epilogue; C/D layout: col = lane&15, row = (lane>>4)*4 + v ----
    const long m0 = (long)bm * 256 + wm128;
    const int n0 = bn * 256 + wn64;
#pragma unroll
    for (int mf = 0; mf < 8; ++mf) {
#pragma unroll
        for (int nf = 0; nf < 4; ++nf) {
            const int n = n0 + nf * 16 + frow;
            const float bv = bias[n];
#pragma unroll
            for (int v = 0; v < 4; ++v) {
                const long m = m0 + mf * 16 + fquad * 4 + v;
                float val = acc[mf][nf][v] + bv;
                if (MODE == 1) {
                    obf[m * NN + n] = f2bf(val);
                    if ((((int)m) & (SS - 1)) == (SS - 1))
                        lf2out[(m >> 12) * NN + n] = val;   // new lf2 cache (f32)
                } else {
                    val += xres[m * NN + n];                // residual in f32
                    yout[m * NN + n] = val;
                }
            }
        }
    }
}

// ---------- RMSNorm (in-place on d_out rows) ----------

__global__ void rmsnorm_inplace(float* __restrict__ y, const float* __restrict__ lnw) {
    const long r = blockIdx.x;
    float* row = y + r * DD;
    const int tid = threadIdx.x;

    float4 v0 = *(float4*)(row + tid * 4);
    float4 v1 = *(float4*)(row + 1024 + tid * 4);
    float s = v0.x * v0.x + v0.y * v0.y + v0.z * v0.z + v0.w * v0.w
            + v1.x * v1.x + v1.y * v1.y + v1.z * v1.z + v1.w * v1.w;
#pragma unroll
    for (int off = 32; off; off >>= 1) s += __shfl_xor(s, off, 64);

    __shared__ float red[4];
    if ((tid & 63) == 0) red[tid >> 6] = s;
    __syncthreads();
    float tot = red[0] + red[1] + red[2] + red[3];
    float inv = rsqrtf(tot * (1.0f / DD) + EPSV);

    float4 w0 = *(const float4*)(lnw + tid * 4);
    float4 w1 = *(const float4*)(lnw + 1024 + tid * 4);
    v0.x *= inv * w0.x; v0.y *= inv * w0.y; v0.z *= inv * w0.z; v0.w *= inv * w0.w;
    v1.x *= inv * w1.x; v1.y *= inv * w1.y; v1.z *= inv * w1.z; v1.w *= inv * w1.w;
    *(float4*)(row + tid * 4) = v0;
    *(float4*)(row + 1024 + tid * 4) = v1;
}

// lf1 = x[:, S-1, :]  (f32 copy, B*D = 8192 elems)
__global__ void lf1_copy(const float* __restrict__ x, float* __restrict__ out) {
    int idx = blockIdx.x * 256 + threadIdx.x;   // 0..8191
    int b = idx >> 11;
    int d = idx & (DD - 1);
    out[idx] = x[((long)b * SS + (SS - 1)) * DD + d];
}

// ---------- launch ----------

extern "C" void kernel_launch(void* const* d_in, const int* in_sizes, int n_in,
                              void* d_out, int out_size, void* d_ws, size_t ws_size,
                              hipStream_t stream) {
    const float* x    = (const float*)d_in[0];   // [M, D]
    const float* lf1c = (const float*)d_in[1];   // [B, D]
    const float* lf2c = (const float*)d_in[2];   // [B, DH]
    const float* w1   = (const float*)d_in[3];   // [DH, D, 2]
    const float* b1   = (const float*)d_in[4];   // [DH]
    const float* w2   = (const float*)d_in[5];   // [D, DH, 2]
    const float* b2   = (const float*)d_in[6];   // [D]
    const float* lnw  = (const float*)d_in[7];   // [D]

    float* out    = (float*)d_out;                        // lf_output [M, D]
    float* lf1out = out + (long)MM * DD;                  // [B, D]
    float* lf2out = lf1out + (long)BB * DD;               // [B, DH]

    char* ws = (char*)d_ws;
    u16* Xbf  = (u16*)ws; ws += (long)MM * DD * 2;        // 67.1 MB
    u16* o1bf = (u16*)ws; ws += (long)MM * DH * 2;        // 33.6 MB
    u16* W1b  = (u16*)ws; ws += (long)DH * (2 * DD) * 2;  // 8.4 MB
    u16* W2b  = (u16*)ws; ws += (long)DD * (2 * DH) * 2;  // 8.4 MB
    u16* c1   = (u16*)ws; ws += (long)BB * DD * 2;
    u16* c2   = (u16*)ws; ws += (long)BB * DH * 2;

    // 1) converts & weight packing
    cvt_f32_bf16<<<32768, 256, 0, stream>>>(x, Xbf, (long)MM * DD / 4);
    cvt_f32_bf16<<<8, 256, 0, stream>>>(lf1c, c1, (long)BB * DD / 4);
    cvt_f32_bf16<<<4, 256, 0, stream>>>(lf2c, c2, (long)BB * DH / 4);
    pack_w<<<(DH * DD) / 256, 256, 0, stream>>>(w1, W1b, 11);   // Dd = D = 2048
    pack_w<<<(DD * DH) / 256, 256, 0, stream>>>(w2, W2b, 10);   // Dd = DH = 1024

    // 2) conv1 GEMM: [M, 2D] x [2D, DH] -> o1 bf16 (+ lf2 rows f32)
    gemm2tap<DD, 1><<<dim3(MM / 256, DH / 256), 512, 0, stream>>>(
        Xbf, c1, W1b, b1, o1bf, lf2out, nullptr, nullptr);

    // 3) conv2 GEMM: [M, 2DH] x [2DH, D] -> y = o2 + x (f32, into d_out)
    gemm2tap<DH, 2><<<dim3(MM / 256, DD / 256), 512, 0, stream>>>(
        o1bf, c2, W2b, b2, nullptr, nullptr, x, out);

    // 4) RMSNorm in place + lf1 cache copy
    rmsnorm_inplace<<<MM, 256, 0, stream>>>(out, lnw);
    lf1_copy<<<BB * DD / 256, 256, 0, stream>>>(x, lf1out);
}

// Round 3
// 555.400 us; speedup vs baseline: 1.0350x; 1.0281x over previous
//
#include <hip/hip_runtime.h>
#include <cstdint>

// Problem constants (LocalizedFiltering: B=4, S=4096, D=2048, DH=1024)
#define BB 4
#define SS 4096           // power of 2: t = r & 4095, b = r >> 12
#define DD 2048
#define DH 1024
#define MM (BB * SS)      // 16384 rows
#define EPSV 1e-6f

typedef unsigned short u16;
typedef __bf16 bf16x8 __attribute__((ext_vector_type(8)));
typedef float f32x4 __attribute__((ext_vector_type(4)));

// ---------- helpers ----------

__device__ __forceinline__ u16 f2bf(float f) {           // RNE f32 -> bf16 bits
    uint32_t u = __float_as_uint(f);
    u += 0x7fffu + ((u >> 16) & 1u);
    return (u16)(u >> 16);
}

// async global->LDS, 16B per lane. LDS dest is wave-uniform base + lane*16.
__device__ __forceinline__ void async16(const void* g, void* l) {
    __builtin_amdgcn_global_load_lds(
        (const __attribute__((address_space(1))) uint32_t*)g,
        (__attribute__((address_space(3))) uint32_t*)l,
        16, 0, 0);
}

#define FENCE asm volatile("" ::: "memory")

// ---------- elementwise converts / packs ----------

__global__ void cvt_f32_bf16(const float* __restrict__ in, u16* __restrict__ out, long n4) {
    long i = (long)blockIdx.x * blockDim.x + threadIdx.x;
    if (i >= n4) return;
    float4 v = *(const float4*)(in + i * 4);
    ushort4 o;
    o.x = f2bf(v.x); o.y = f2bf(v.y); o.z = f2bf(v.z); o.w = f2bf(v.w);
    *(ushort4*)(out + i * 4) = o;
}

// w [Nr, Dd, 2] f32 (tap-interleaved) -> out [Nr, 2*Dd] bf16 with tap0 cols [0,Dd), tap1 [Dd,2Dd)
__global__ void pack_w(const float* __restrict__ in, u16* __restrict__ out, int dshift) {
    int idx = blockIdx.x * 256 + threadIdx.x;   // pair index: e*Dd + d
    int Dd = 1 << dshift;
    int e = idx >> dshift;
    int d = idx & (Dd - 1);
    float2 v = *(const float2*)(in + (long)idx * 2);
    long rowbase = (long)e * (Dd * 2);
    out[rowbase + d] = f2bf(v.x);          // tap 0 (prev timestep)
    out[rowbase + Dd + d] = f2bf(v.y);     // tap 1 (current timestep)
}

// ---------- shifted 2-tap GEMM: 256x256 tile, 8-wave, ring-4 K-half pipeline ----------
//
// ROUND-3 STRUCTURE: one s_barrier per K-half step (was 2 per phase / 4 per tile).
// Rationale (round-2 post-mortem): MFMA pipe needs 2483 cyc/tile/SIMD, LDS pipe
// ~2800 cyc/tile/CU; the leading barrier serialized the two bursts -> 6600 cyc
// observed. The leading barrier is redundant: every wave's ds_reads retire
// before it ARRIVES at its barrier (reads feed MFMAs via compiler lgkm waits),
// so the single trailing barrier already provides the WAR guarantee, and
// staged-data RAW is provided by per-wave vmcnt + the previous barrier.
// B-frags are read FIRST so the compiler's fine-grained lgkmcnt releases the
// first MFMA after 5 reads; thereafter 4 MFMAs (~77 cyc) unlock per A-read
// (~96 cyc) -> LDS service overlaps matrix pipe within a step. s_barrier does
// not wait on in-flight MFMAs, so the next step's reads also overlap the
// previous step's MFMA drain.
//
// LDS (128 KiB): ring of 4 K-half slots per matrix, slot = step & 3.
//   A slot u at elems [u*8192, +8192): 256 rows x 32 k-elems (row r at r*32+k).
//   B slot u at 32768 + u*8192, same shape (rows = output cols).
// Swizzle (unchanged, verified conflict-free rounds 1-2): 16B-slot s of row r
//   holds global chunk s ^ ((r>>1)&3); staged via pre-swizzled GLOBAL address
//   (global_load_lds dest is linear base+lane*16), read with the same XOR.
// Step s (K-half index, 0..NS-1; tile = s>>1, K-offset = s*32 elems):
//   { 4 ds_read_b128 B-frags, 8 A-frags   (slot s&3)
//     stage 4 global_load_lds for step s+3 (slot (s+3)&3)
//     setprio(1); 32 MFMA (compiler-interleaved lgkm waits); setprio(0)
//     s_waitcnt vmcnt(8); s_barrier }
// WAR: slot (s+3)&3 == slot (s-1)&3 was last read in step s-1; those reads
//   retired before each wave passed barrier B_{s-1}, which precedes this
//   step's stage issue. RAW: step s+1's loads (issued s-2) are older than the
//   8 newest outstanding (steps s+2, s+3) -> vmcnt(8) at B_s drains them.
// Prologue: stage steps 0,1,2 (12 loads), vmcnt(8) -> step 0 landed, barrier.
// Tail (last 4 steps): stage only step NS-1; vmcnt 8/4/0/none.
//
// C[r,n] = sum_{k<KD} Bt[n,k]*Aprev[r,k] + sum_{k<KD} Bt[n,KD+k]*Acur[r,k]
// Aprev row r = (r%S==0) ? cache[r/S] : A[r-1]
// Step u sources Aprev when u < NT (K-offset u*32 < KD), else Acur at u*32-KD.
// MODE 1: out bf16 [M,NN] + bias; rows with t==S-1 also stored f32 to lf2out
// MODE 2: out f32  [M,NN] + bias + residual xres
template <int KD, int MODE>
__launch_bounds__(512, 2)
__global__ void gemm2tap(const u16* __restrict__ A,       // [M, KD] bf16
                         const u16* __restrict__ cache,   // [B, KD] bf16
                         const u16* __restrict__ Bt,      // [NN, 2*KD] bf16
                         const float* __restrict__ bias,  // [NN]
                         u16* __restrict__ obf,           // MODE 1
                         float* __restrict__ lf2out,      // MODE 1
                         const float* __restrict__ xres,  // MODE 2
                         float* __restrict__ yout)        // MODE 2
{
    constexpr int KTOT = 2 * KD;
    constexpr int NT = KTOT / 64;      // K-tiles of 64
    constexpr int NS = 2 * NT;         // K-half steps of 32
    constexpr int NN = (MODE == 1) ? DH : DD;
    static_assert(NS % 4 == 0 && NS >= 8, "ring-4 schedule needs NS % 4 == 0, NS >= 8");

    const int tid = threadIdx.x;
    const int lane = tid & 63;
    const int wave = tid >> 6;         // 8 waves: wm = wave>>2 (2), wn = wave&3 (4)
    const int bm = blockIdx.x;
    const int bn = blockIdx.y;

    __shared__ __align__(16) u16 sm[65536];   // 128 KiB

    // ---- staging addressing ----
    const int srow = wave * 16 + (lane >> 2);          // row within 128-row half
    const int skc  = (lane & 3) ^ ((lane >> 3) & 3);   // pre-swizzled global chunk
    const int sRowA = wave * 512;                      // wave-uniform LDS elem offset

    const u16 *aPrev0, *aPrev1, *aCur0, *aCur1, *bPtr0, *bPtr1;
    {
        long r0 = (long)bm * 256 + srow;
        long r1 = r0 + 128;
        aCur0 = A + r0 * KD + skc * 8;
        aCur1 = A + r1 * KD + skc * 8;
        aPrev0 = ((((int)r0) & (SS - 1)) == 0) ? (cache + (r0 >> 12) * KD + skc * 8)
                                               : (A + (r0 - 1) * KD + skc * 8);
        aPrev1 = ((((int)r1) & (SS - 1)) == 0) ? (cache + (r1 >> 12) * KD + skc * 8)
                                               : (A + (r1 - 1) * KD + skc * 8);
        long n0l = (long)bn * 256 + srow;
        bPtr0 = Bt + n0l * KTOT + skc * 8;
        bPtr1 = Bt + (n0l + 128) * KTOT + skc * 8;
    }

    // stage K-half step U_ into ring slot SLOT_ (A: rows 0..127 then 128..255; B same)
#define STAGE(SLOT_, U_) do {                                                  \
        const int _u = (U_);                                                   \
        const u16 *_g0, *_g1;                                                  \
        if (_u < NT) { _g0 = aPrev0 + _u * 32; _g1 = aPrev1 + _u * 32; }       \
        else { _g0 = aCur0 + (_u - NT) * 32; _g1 = aCur1 + (_u - NT) * 32; }   \
        async16(_g0, sm + (SLOT_) * 8192 + sRowA);                             \
        async16(_g1, sm + (SLOT_) * 8192 + 4096 + sRowA);                      \
        async16(bPtr0 + _u * 32, sm + 32768 + (SLOT_) * 8192 + sRowA);         \
        async16(bPtr1 + _u * 32, sm + 32768 + (SLOT_) * 8192 + 4096 + sRowA);  \
    } while (0)

    // ---- fragment read addressing ----
    const int frow = lane & 15;
    const int fquad = lane >> 4;
    const int wm128 = (wave >> 2) * 128;
    const int wn64  = (wave & 3) * 64;
    const int fq8s = (fquad ^ ((frow >> 1) & 3)) * 8;  // swizzled 16B chunk (elems)
    const int afb = (wm128 + frow) * 32 + fq8s;
    const int bfb = (wn64 + frow) * 32 + fq8s;

    f32x4 acc[8][4];
#pragma unroll
    for (int i = 0; i < 8; ++i)
#pragma unroll
        for (int j = 0; j < 4; ++j)
            acc[i][j] = (f32x4){0.f, 0.f, 0.f, 0.f};

#define MFMA_(D_, A_, B_) D_ = __builtin_amdgcn_mfma_f32_16x16x32_bf16(A_, B_, D_, 0, 0, 0)

    // One K-half step: reads (B first), stage for U3_, MFMA, vmcnt, one barrier.
#define STEP(SLOT_, U3_, DOSTG_, VMS_)                                         \
  {                                                                            \
    const u16* aro = sm + (SLOT_) * 8192;                                      \
    const u16* bro = sm + 32768 + (SLOT_) * 8192;                              \
    bf16x8 bq[4], af[8];                                                       \
    _Pragma("unroll")                                                          \
    for (int nf = 0; nf < 4; ++nf)                                             \
        bq[nf] = *(const bf16x8*)(bro + bfb + nf * 512);                       \
    _Pragma("unroll")                                                          \
    for (int mf = 0; mf < 8; ++mf)                                             \
        af[mf] = *(const bf16x8*)(aro + afb + mf * 512);                       \
    if (DOSTG_) STAGE((((SLOT_) + 3) & 3), (U3_));                             \
    __builtin_amdgcn_s_setprio(1);                                             \
    _Pragma("unroll")                                                          \
    for (int mf = 0; mf < 8; ++mf)                                             \
        _Pragma("unroll")                                                      \
        for (int nf = 0; nf < 4; ++nf)                                         \
            MFMA_(acc[mf][nf], af[mf], bq[nf]);                                \
    __builtin_amdgcn_s_setprio(0);                                             \
    asm volatile(VMS_ ::: "memory");                                           \
    FENCE; __builtin_amdgcn_s_barrier(); FENCE;                                \
  }

    // ---- prologue: stage steps 0,1,2 (12 loads) in issue order ----
    STAGE(0, 0); FENCE;
    STAGE(1, 1); FENCE;
    STAGE(2, 2);
    asm volatile("s_waitcnt vmcnt(8)" ::: "memory");   // step 0 landed
    FENCE; __builtin_amdgcn_s_barrier(); FENCE;

    // ---- main loop: steps 0 .. NS-5 (full staging, uniform vmcnt(8)) ----
    for (int s = 0; s < NS - 4; s += 4) {
        STEP(0, s + 3, 1, "s_waitcnt vmcnt(8)");
        STEP(1, s + 4, 1, "s_waitcnt vmcnt(8)");
        STEP(2, s + 5, 1, "s_waitcnt vmcnt(8)");
        STEP(3, s + 6, 1, "s_waitcnt vmcnt(8)");
    }
    // ---- tail: steps NS-4 .. NS-1 ----
    STEP(0, NS - 1, 1, "s_waitcnt vmcnt(8)");   // stages the last K-half
    STEP(1, 0, 0, "s_waitcnt vmcnt(4)");
    STEP(2, 0, 0, "s_waitcnt vmcnt(0)");
    STEP(3, 0, 0, "");                          // last step: no wait needed

#undef STEP
#undef STAGE

    // ---- epilogue; C/D layout: col = lane&15, row = (lane>>4)*4 + v ----
    const long m0 = (long)bm * 256 + wm128;
    const int n0 = bn * 256 + wn64;
#pragma unroll
    for (int mf = 0; mf < 8; ++mf) {
#pragma unroll
        for (int nf = 0; nf < 4; ++nf) {
            const int n = n0 + nf * 16 + frow;
            const float bv = bias[n];
#pragma unroll
            for (int v = 0; v < 4; ++v) {
                const long m = m0 + mf * 16 + fquad * 4 + v;
                float val = acc[mf][nf][v] + bv;
                if (MODE == 1) {
                    obf[m * NN + n] = f2bf(val);
                    if ((((int)m) & (SS - 1)) == (SS - 1))
                        lf2out[(m >> 12) * NN + n] = val;   // new lf2 cache (f32)
                } else {
                    val += xres[m * NN + n];                // residual in f32
                    yout[m * NN + n] = val;
                }
            }
        }
    }
}

// ---------- RMSNorm (in-place on d_out rows) ----------

__global__ void rmsnorm_inplace(float* __restrict__ y, const float* __restrict__ lnw) {
    const long r = blockIdx.x;
    float* row = y + r * DD;
    const int tid = threadIdx.x;

    float4 v0 = *(float4*)(row + tid * 4);
    float4 v1 = *(float4*)(row + 1024 + tid * 4);
    float s = v0.x * v0.x + v0.y * v0.y + v0.z * v0.z + v0.w * v0.w
            + v1.x * v1.x + v1.y * v1.y + v1.z * v1.z + v1.w * v1.w;
#pragma unroll
    for (int off = 32; off; off >>= 1) s += __shfl_xor(s, off, 64);

    __shared__ float red[4];
    if ((tid & 63) == 0) red[tid >> 6] = s;
    __syncthreads();
    float tot = red[0] + red[1] + red[2] + red[3];
    float inv = rsqrtf(tot * (1.0f / DD) + EPSV);

    float4 w0 = *(const float4*)(lnw + tid * 4);
    float4 w1 = *(const float4*)(lnw + 1024 + tid * 4);
    v0.x *= inv * w0.x; v0.y *= inv * w0.y; v0.z *= inv * w0.z; v0.w *= inv * w0.w;
    v1.x *= inv * w1.x; v1.y *= inv * w1.y; v1.z *= inv * w1.z; v1.w *= inv * w1.w;
    *(float4*)(row + tid * 4) = v0;
    *(float4*)(row + 1024 + tid * 4) = v1;
}

// lf1 = x[:, S-1, :]  (f32 copy, B*D = 8192 elems)
__global__ void lf1_copy(const float* __restrict__ x, float* __restrict__ out) {
    int idx = blockIdx.x * 256 + threadIdx.x;   // 0..8191
    int b = idx >> 11;
    int d = idx & (DD - 1);
    out[idx] = x[((long)b * SS + (SS - 1)) * DD + d];
}

// ---------- launch ----------

extern "C" void kernel_launch(void* const* d_in, const int* in_sizes, int n_in,
                              void* d_out, int out_size, void* d_ws, size_t ws_size,
                              hipStream_t stream) {
    const float* x    = (const float*)d_in[0];   // [M, D]
    const float* lf1c = (const float*)d_in[1];   // [B, D]
    const float* lf2c = (const float*)d_in[2];   // [B, DH]
    const float* w1   = (const float*)d_in[3];   // [DH, D, 2]
    const float* b1   = (const float*)d_in[4];   // [DH]
    const float* w2   = (const float*)d_in[5];   // [D, DH, 2]
    const float* b2   = (const float*)d_in[6];   // [D]
    const float* lnw  = (const float*)d_in[7];   // [D]

    float* out    = (float*)d_out;                        // lf_output [M, D]
    float* lf1out = out + (long)MM * DD;                  // [B, D]
    float* lf2out = lf1out + (long)BB * DD;               // [B, DH]

    char* ws = (char*)d_ws;
    u16* Xbf  = (u16*)ws; ws += (long)MM * DD * 2;        // 67.1 MB
    u16* o1bf = (u16*)ws; ws += (long)MM * DH * 2;        // 33.6 MB
    u16* W1b  = (u16*)ws; ws += (long)DH * (2 * DD) * 2;  // 8.4 MB
    u16* W2b  = (u16*)ws; ws += (long)DD * (2 * DH) * 2;  // 8.4 MB
    u16* c1   = (u16*)ws; ws += (long)BB * DD * 2;
    u16* c2   = (u16*)ws; ws += (long)BB * DH * 2;

    // 1) converts & weight packing
    cvt_f32_bf16<<<32768, 256, 0, stream>>>(x, Xbf, (long)MM * DD / 4);
    cvt_f32_bf16<<<8, 256, 0, stream>>>(lf1c, c1, (long)BB * DD / 4);
    cvt_f32_bf16<<<4, 256, 0, stream>>>(lf2c, c2, (long)BB * DH / 4);
    pack_w<<<(DH * DD) / 256, 256, 0, stream>>>(w1, W1b, 11);   // Dd = D = 2048
    pack_w<<<(DD * DH) / 256, 256, 0, stream>>>(w2, W2b, 10);   // Dd = DH = 1024

    // 2) conv1 GEMM: [M, 2D] x [2D, DH] -> o1 bf16 (+ lf2 rows f32)
    gemm2tap<DD, 1><<<dim3(MM / 256, DH / 256), 512, 0, stream>>>(
        Xbf, c1, W1b, b1, o1bf, lf2out, nullptr, nullptr);

    // 3) conv2 GEMM: [M, 2DH] x [2DH, D] -> y = o2 + x (f32, into d_out)
    gemm2tap<DH, 2><<<dim3(MM / 256, DD / 256), 512, 0, stream>>>(
        o1bf, c2, W2b, b2, nullptr, nullptr, x, out);

    // 4) RMSNorm in place + lf1 cache copy
    rmsnorm_inplace<<<MM, 256, 0, stream>>>(out, lnw);
    lf1_copy<<<BB * DD / 256, 256, 0, stream>>>(x, lf1out);
}